// Round 3
// baseline (806.034 us; speedup 1.0000x reference)
//
#include <hip/hip_runtime.h>
#include <hip/hip_bf16.h>

#define D_IN  128
#define D_HID 16
#define N_CLS 2

#define FE 0   // edge_index storage: 0 = int32, 1 = int64 (doc says int32; keep safety)

// ---------------- edge dtype detection (1 block) ----------------
// int64 little-endian values < 2^31: every odd 32-bit word is 0.
// int32: odd words are node ids, nonzero a.s.
__global__ void k_detect(const int* __restrict__ ev, int* __restrict__ flags) {
    __shared__ int sE;
    if (threadIdx.x == 0) sE = 0;
    __syncthreads();
    if (ev[2 * threadIdx.x + 1] != 0) atomicOr(&sE, 1);
    __syncthreads();
    if (threadIdx.x == 0) flags[FE] = sE ? 0 : 1;
}

template<bool I64>
__device__ __forceinline__ int lde(const void* p, size_t i) {
    if constexpr (I64) return (int)((const long long*)p)[i];
    else               return ((const int*)p)[i];
}

// ---------------- degree / norm ----------------
__global__ void k_deg_init(unsigned int* __restrict__ deg, int n) {
    int i = blockIdx.x * blockDim.x + threadIdx.x;
    if (i < n) deg[i] = 1u;  // self loop
}

template<bool I64>
__global__ void k_deg_count(const void* __restrict__ ei, unsigned int* __restrict__ deg,
                            int E, const int* __restrict__ flags) {
    if (flags[FE] != (int)I64) return;
    int e = blockIdx.x * blockDim.x + threadIdx.x;
    if (e < E) atomicAdd(&deg[lde<I64>(ei, (size_t)E + e)], 1u);
}

__global__ void k_dinv(float* __restrict__ dinv, int n) {
    int i = blockIdx.x * blockDim.x + threadIdx.x;
    if (i < n) {
        unsigned int u = ((const unsigned int*)dinv)[i];
        dinv[i] = rsqrtf((float)u);   // deg >= 1 always
    }
}

// ---------------- layer 1: h1 = x @ W1 ----------------
// 16 lanes per node row; W1 (128x16 fp32) staged in LDS.
__global__ void k_gemm1(const float* __restrict__ x, const float* __restrict__ W1,
                        float* __restrict__ h1, int n) {
    __shared__ float w[D_IN * D_HID];  // 8 KiB
    for (int i = threadIdx.x; i < D_IN * D_HID; i += blockDim.x)
        w[i] = W1[i];
    __syncthreads();
    int tid = blockIdx.x * blockDim.x + threadIdx.x;
    int node = tid >> 4, f = tid & 15;
    if (node >= n) return;
    const float4* xr = (const float4*)(x + (size_t)node * D_IN);
    float acc = 0.f;
#pragma unroll
    for (int k4 = 0; k4 < D_IN / 4; ++k4) {
        float4 v = xr[k4];
        int k = k4 * 4;
        acc += v.x * w[(k + 0) * D_HID + f];
        acc += v.y * w[(k + 1) * D_HID + f];
        acc += v.z * w[(k + 2) * D_HID + f];
        acc += v.w * w[(k + 3) * D_HID + f];
    }
    h1[tid] = acc;
}

// a1 = b1 + dinv^2 * h1   (bias + self-loop term)
__global__ void k_a1_init(const float* __restrict__ h1, const float* __restrict__ dinv,
                          const float* __restrict__ b1, float* __restrict__ a1, int n) {
    int tid = blockIdx.x * blockDim.x + threadIdx.x;
    if (tid >= n * D_HID) return;
    int node = tid >> 4, f = tid & 15;
    float di = dinv[node];
    a1[tid] = b1[f] + di * di * h1[tid];
}

// edge-parallel scatter: a1[dst,f] += h1[src,f] * dinv[src]*dinv[dst]
template<bool I64>
__global__ void k_agg1(const void* __restrict__ ei, const float* __restrict__ dinv,
                       const float* __restrict__ h1, float* __restrict__ a1,
                       int E, const int* __restrict__ flags) {
    if (flags[FE] != (int)I64) return;
    int tid = blockIdx.x * blockDim.x + threadIdx.x;
    int e = tid >> 4, f = tid & 15;
    if (e >= E) return;
    int s = lde<I64>(ei, (size_t)e);
    int d = lde<I64>(ei, (size_t)E + e);
    float norm = dinv[s] * dinv[d];
    atomicAdd(&a1[(size_t)d * D_HID + f], h1[(size_t)s * D_HID + f] * norm);
}

// ---------------- layer 2: h2 = relu(a1) @ W2 ----------------
__global__ void k_relu_gemm2(const float* __restrict__ a1, const float* __restrict__ W2,
                             float* __restrict__ h2, int n) {
    int node = blockIdx.x * blockDim.x + threadIdx.x;
    if (node >= n) return;
    float c0 = 0.f, c1 = 0.f;
    const float* row = a1 + (size_t)node * D_HID;
#pragma unroll
    for (int f = 0; f < D_HID; ++f) {
        float r = fmaxf(row[f], 0.f);
        c0 += r * W2[f * N_CLS + 0];
        c1 += r * W2[f * N_CLS + 1];
    }
    h2[(size_t)node * 2 + 0] = c0;
    h2[(size_t)node * 2 + 1] = c1;
}

__global__ void k_a2_init(const float* __restrict__ h2, const float* __restrict__ dinv,
                          const float* __restrict__ b2, float* __restrict__ a2, int n) {
    int tid = blockIdx.x * blockDim.x + threadIdx.x;
    if (tid >= n * N_CLS) return;
    int node = tid >> 1, c = tid & 1;
    float di = dinv[node];
    a2[tid] = b2[c] + di * di * h2[tid];
}

template<bool I64>
__global__ void k_agg2(const void* __restrict__ ei, const float* __restrict__ dinv,
                       const float* __restrict__ h2, float* __restrict__ a2,
                       int E, const int* __restrict__ flags) {
    if (flags[FE] != (int)I64) return;
    int e = blockIdx.x * blockDim.x + threadIdx.x;
    if (e >= E) return;
    int s = lde<I64>(ei, (size_t)e);
    int d = lde<I64>(ei, (size_t)E + e);
    float norm = dinv[s] * dinv[d];
    atomicAdd(&a2[(size_t)d * 2 + 0], h2[(size_t)s * 2 + 0] * norm);
    atomicAdd(&a2[(size_t)d * 2 + 1], h2[(size_t)s * 2 + 1] * norm);
}

// ---------------- log_softmax, fp32 output ----------------
__global__ void k_lsm(const float* __restrict__ a2, float* __restrict__ out, int n) {
    int node = blockIdx.x * blockDim.x + threadIdx.x;
    if (node >= n) return;
    float v0 = a2[(size_t)node * 2 + 0];
    float v1 = a2[(size_t)node * 2 + 1];
    float m = fmaxf(v0, v1);
    float lse = m + logf(expf(v0 - m) + expf(v1 - m));
    out[(size_t)node * 2 + 0] = v0 - lse;
    out[(size_t)node * 2 + 1] = v1 - lse;
}

extern "C" void kernel_launch(void* const* d_in, const int* in_sizes, int n_in,
                              void* d_out, int out_size, void* d_ws, size_t ws_size,
                              hipStream_t stream) {
    const float* x  = (const float*)d_in[0];
    const void*  ei = d_in[1];
    const float* W1 = (const float*)d_in[2];
    const float* b1 = (const float*)d_in[3];
    const float* W2 = (const float*)d_in[4];
    const float* b2 = (const float*)d_in[5];
    float* out = (float*)d_out;

    const int N = in_sizes[0] / D_IN;      // 100000
    const int E = in_sizes[1] / 2;         // 3200000

    // workspace layout (bytes, 128-aligned); round 2 proved ws_size >= 14.8MB
    char* ws = (char*)d_ws;
    float* dinv  = (float*)(ws + 0);            // N f32 (also uint deg)
    float* h1    = (float*)(ws + 400128);       // N*16 f32
    float* a1    = (float*)(ws + 6800256);      // N*16 f32
    float* h2    = (float*)(ws + 13200384);     // N*2  f32
    float* a2    = (float*)(ws + 14000512);     // N*2  f32
    int*   flags = (int*)  (ws + 14800640);     // 1 int

    const int B = 256;
    dim3 blk(B);

    k_detect<<<dim3(1), blk, 0, stream>>>((const int*)ei, flags);

    k_deg_init<<<dim3((N + B - 1) / B), blk, 0, stream>>>((unsigned int*)dinv, N);
    k_deg_count<false><<<dim3((E + B - 1) / B), blk, 0, stream>>>(ei, (unsigned int*)dinv, E, flags);
    k_deg_count<true ><<<dim3((E + B - 1) / B), blk, 0, stream>>>(ei, (unsigned int*)dinv, E, flags);
    k_dinv<<<dim3((N + B - 1) / B), blk, 0, stream>>>(dinv, N);

    dim3 g_nh((N * D_HID + B - 1) / B);
    k_gemm1<<<g_nh, blk, 0, stream>>>(x, W1, h1, N);
    k_a1_init<<<g_nh, blk, 0, stream>>>(h1, dinv, b1, a1, N);

    dim3 g_eh(((size_t)E * D_HID + B - 1) / B);
    k_agg1<false><<<g_eh, blk, 0, stream>>>(ei, dinv, h1, a1, E, flags);
    k_agg1<true ><<<g_eh, blk, 0, stream>>>(ei, dinv, h1, a1, E, flags);

    dim3 g_n((N + B - 1) / B);
    k_relu_gemm2<<<g_n, blk, 0, stream>>>(a1, W2, h2, N);

    dim3 g_n2((N * N_CLS + B - 1) / B);
    k_a2_init<<<g_n2, blk, 0, stream>>>(h2, dinv, b2, a2, N);

    dim3 g_e((E + B - 1) / B);
    k_agg2<false><<<g_e, blk, 0, stream>>>(ei, dinv, h2, a2, E, flags);
    k_agg2<true ><<<g_e, blk, 0, stream>>>(ei, dinv, h2, a2, E, flags);

    k_lsm<<<g_n, blk, 0, stream>>>(a2, out, N);
}

// Round 4
// 634.635 us; speedup vs baseline: 1.2701x; 1.2701x over previous
//
#include <hip/hip_runtime.h>
#include <hip/hip_bf16.h>

#define D_IN  128
#define D_HID 16
#define N_CLS 2

#define FE 0   // edge_index storage: 0 = int32, 1 = int64

// ---------------- edge dtype detection (1 block) ----------------
__global__ void k_detect(const int* __restrict__ ev, int* __restrict__ flags) {
    __shared__ int sE;
    if (threadIdx.x == 0) sE = 0;
    __syncthreads();
    if (ev[2 * threadIdx.x + 1] != 0) atomicOr(&sE, 1);
    __syncthreads();
    if (threadIdx.x == 0) flags[FE] = sE ? 0 : 1;
}

template<bool I64>
__device__ __forceinline__ int lde(const void* p, size_t i) {
    if constexpr (I64) return (int)((const long long*)p)[i];
    else               return ((const int*)p)[i];
}

// ---------------- degree ----------------
__global__ void k_deg_init(unsigned int* __restrict__ deg, int n) {
    int i = blockIdx.x * blockDim.x + threadIdx.x;
    if (i < n) deg[i] = 1u;  // self loop
}

template<bool I64>
__global__ void k_deg_count(const void* __restrict__ ei, unsigned int* __restrict__ deg,
                            int E, const int* __restrict__ flags) {
    if (flags[FE] != (int)I64) return;
    int e = blockIdx.x * blockDim.x + threadIdx.x;
    if (e < E) atomicAdd(&deg[lde<I64>(ei, (size_t)E + e)], 1u);
}

__global__ void k_dinv(const unsigned int* __restrict__ deg, float* __restrict__ dinv, int n) {
    int i = blockIdx.x * blockDim.x + threadIdx.x;
    if (i < n) dinv[i] = rsqrtf((float)deg[i]);   // deg >= 1 always
}

// ---------------- CSR build: scan of (deg-1), then fill ----------------
// scan1: per-256-block inclusive scan of edge-degree into row_ptr[i+1]; block sums out.
__global__ void k_scan1(const unsigned int* __restrict__ deg, int* __restrict__ row_ptr,
                        int* __restrict__ bsums, int n) {
    __shared__ int s[256];
    int tid = threadIdx.x;
    int i = blockIdx.x * 256 + tid;
    int v = (i < n) ? (int)(deg[i] - 1u) : 0;
    s[tid] = v;
    __syncthreads();
#pragma unroll
    for (int off = 1; off < 256; off <<= 1) {
        int t = (tid >= off) ? s[tid - off] : 0;
        __syncthreads();
        s[tid] += t;
        __syncthreads();
    }
    if (i < n) row_ptr[i + 1] = s[tid];
    if (tid == 255) bsums[blockIdx.x] = s[255];
}

// scan2: single block (1024 threads) exclusive-scans the block sums in place.
__global__ void k_scan2(int* __restrict__ bsums, int nb) {
    __shared__ int s[1024];
    int tid = threadIdx.x;
    int v = (tid < nb) ? bsums[tid] : 0;
    s[tid] = v;
    __syncthreads();
#pragma unroll
    for (int off = 1; off < 1024; off <<= 1) {
        int t = (tid >= off) ? s[tid - off] : 0;
        __syncthreads();
        s[tid] += t;
        __syncthreads();
    }
    if (tid < nb) bsums[tid] = s[tid] - v;   // exclusive
}

// scan3: add block offsets; derive cursor (exclusive start). cursor aliases deg.
__global__ void k_scan3(int* __restrict__ row_ptr, const int* __restrict__ bsums,
                        unsigned int* __restrict__ deg_cursor, int n) {
    int i = blockIdx.x * 256 + threadIdx.x;
    if (i >= n) return;
    int degE = (int)(deg_cursor[i] - 1u);
    int val = row_ptr[i + 1] + bsums[blockIdx.x];
    row_ptr[i + 1] = val;
    deg_cursor[i] = (unsigned int)(val - degE);
    if (i == 0) row_ptr[0] = 0;
}

template<bool I64>
__global__ void k_fill(const void* __restrict__ ei, unsigned int* __restrict__ cursor,
                       int* __restrict__ csr_src, int E, const int* __restrict__ flags) {
    if (flags[FE] != (int)I64) return;
    int e = blockIdx.x * blockDim.x + threadIdx.x;
    if (e >= E) return;
    int s = lde<I64>(ei, (size_t)e);
    int d = lde<I64>(ei, (size_t)E + e);
    unsigned int pos = atomicAdd(&cursor[d], 1u);
    csr_src[pos] = s;
}

// ---------------- layer 1 GEMM: g1 = dinv * (x @ W1) ----------------
__global__ void k_gemm1(const float* __restrict__ x, const float* __restrict__ W1,
                        const float* __restrict__ dinv, float* __restrict__ g1, int n) {
    __shared__ float w[D_IN * D_HID];  // 8 KiB
    for (int i = threadIdx.x; i < D_IN * D_HID; i += blockDim.x)
        w[i] = W1[i];
    __syncthreads();
    int tid = blockIdx.x * blockDim.x + threadIdx.x;
    int node = tid >> 4, f = tid & 15;
    if (node >= n) return;
    const float4* xr = (const float4*)(x + (size_t)node * D_IN);
    float acc = 0.f;
#pragma unroll
    for (int k4 = 0; k4 < D_IN / 4; ++k4) {
        float4 v = xr[k4];
        int k = k4 * 4;
        acc += v.x * w[(k + 0) * D_HID + f];
        acc += v.y * w[(k + 1) * D_HID + f];
        acc += v.z * w[(k + 2) * D_HID + f];
        acc += v.w * w[(k + 3) * D_HID + f];
    }
    g1[tid] = dinv[node] * acc;
}

// ---------------- fused: gather-agg1 + bias + ReLU + GEMM2 -> g2 ----------------
// 16 lanes per node. a1[d,f] = b1[f] + dinv[d]*(g1[d,f] + sum_j g1[src_j,f]);
// h2 = relu(a1) @ W2 via cross-lane reduction; g2[d] = dinv[d]*h2.
__global__ void k_agg1f(const int* __restrict__ csr_src, const int* __restrict__ row_ptr,
                        const float* __restrict__ dinv, const float* __restrict__ g1,
                        const float* __restrict__ b1, const float* __restrict__ W2,
                        float2* __restrict__ g2, int n) {
    int tid = blockIdx.x * blockDim.x + threadIdx.x;
    int node = tid >> 4, f = tid & 15;
    if (node >= n) return;                 // N divisible by 16: never splits a group
    int beg = row_ptr[node], end = row_ptr[node + 1];
    float acc = g1[(size_t)node * D_HID + f];   // self-loop term
    int gbase = (threadIdx.x & 63) & 48;        // 16-lane group base within wave
    for (int j = beg; j < end; j += 16) {
        int m = end - j; if (m > 16) m = 16;
        int myS = (j + f < end) ? csr_src[j + f] : 0;
        for (int k = 0; k < m; ++k) {
            int s = __shfl(myS, gbase + k, 64);
            acc += g1[(size_t)s * D_HID + f];
        }
    }
    float di = dinv[node];
    float r = fmaxf(b1[f] + di * acc, 0.f);
    float c0 = r * W2[f * N_CLS + 0];
    float c1 = r * W2[f * N_CLS + 1];
#pragma unroll
    for (int m = 8; m >= 1; m >>= 1) {
        c0 += __shfl_xor(c0, m, 64);
        c1 += __shfl_xor(c1, m, 64);
    }
    if (f == 0) g2[node] = make_float2(di * c0, di * c1);
}

// ---------------- fused: gather-agg2 + bias + log_softmax -> out ----------------
__global__ void k_agg2lsm(const int* __restrict__ csr_src, const int* __restrict__ row_ptr,
                          const float* __restrict__ dinv, const float2* __restrict__ g2,
                          const float* __restrict__ b2, float2* __restrict__ out, int n) {
    int node = blockIdx.x * blockDim.x + threadIdx.x;
    if (node >= n) return;
    float2 self = g2[node];
    float a0 = self.x, a1 = self.y;
    int beg = row_ptr[node], end = row_ptr[node + 1];
    for (int j = beg; j < end; ++j) {
        float2 t = g2[csr_src[j]];
        a0 += t.x; a1 += t.y;
    }
    float di = dinv[node];
    float v0 = b2[0] + di * a0;
    float v1 = b2[1] + di * a1;
    float mx = fmaxf(v0, v1);
    float lse = mx + logf(expf(v0 - mx) + expf(v1 - mx));
    out[node] = make_float2(v0 - lse, v1 - lse);
}

// =================== fallback (round-3 atomic path, if ws too small) ===================
__global__ void fb_dinv_inplace(float* __restrict__ dinv, int n) {
    int i = blockIdx.x * blockDim.x + threadIdx.x;
    if (i < n) {
        unsigned int u = ((const unsigned int*)dinv)[i];
        dinv[i] = rsqrtf((float)u);
    }
}
__global__ void fb_a1_init(const float* __restrict__ h1, const float* __restrict__ dinv,
                           const float* __restrict__ b1, float* __restrict__ a1, int n) {
    int tid = blockIdx.x * blockDim.x + threadIdx.x;
    if (tid >= n * D_HID) return;
    int node = tid >> 4, f = tid & 15;
    float di = dinv[node];
    a1[tid] = b1[f] + di * di * h1[tid];
}
template<bool I64>
__global__ void fb_agg1(const void* __restrict__ ei, const float* __restrict__ dinv,
                        const float* __restrict__ h1, float* __restrict__ a1,
                        int E, const int* __restrict__ flags) {
    if (flags[FE] != (int)I64) return;
    int tid = blockIdx.x * blockDim.x + threadIdx.x;
    int e = tid >> 4, f = tid & 15;
    if (e >= E) return;
    int s = lde<I64>(ei, (size_t)e);
    int d = lde<I64>(ei, (size_t)E + e);
    float norm = dinv[s] * dinv[d];
    atomicAdd(&a1[(size_t)d * D_HID + f], h1[(size_t)s * D_HID + f] * norm);
}
__global__ void fb_relu_gemm2(const float* __restrict__ a1, const float* __restrict__ W2,
                              float* __restrict__ h2, int n) {
    int node = blockIdx.x * blockDim.x + threadIdx.x;
    if (node >= n) return;
    float c0 = 0.f, c1 = 0.f;
    const float* row = a1 + (size_t)node * D_HID;
#pragma unroll
    for (int f = 0; f < D_HID; ++f) {
        float r = fmaxf(row[f], 0.f);
        c0 += r * W2[f * N_CLS + 0];
        c1 += r * W2[f * N_CLS + 1];
    }
    h2[(size_t)node * 2 + 0] = c0;
    h2[(size_t)node * 2 + 1] = c1;
}
__global__ void fb_a2_init(const float* __restrict__ h2, const float* __restrict__ dinv,
                           const float* __restrict__ b2, float* __restrict__ a2, int n) {
    int tid = blockIdx.x * blockDim.x + threadIdx.x;
    if (tid >= n * N_CLS) return;
    int node = tid >> 1, c = tid & 1;
    float di = dinv[node];
    a2[tid] = b2[c] + di * di * h2[tid];
}
template<bool I64>
__global__ void fb_agg2(const void* __restrict__ ei, const float* __restrict__ dinv,
                        const float* __restrict__ h2, float* __restrict__ a2,
                        int E, const int* __restrict__ flags) {
    if (flags[FE] != (int)I64) return;
    int e = blockIdx.x * blockDim.x + threadIdx.x;
    if (e >= E) return;
    int s = lde<I64>(ei, (size_t)e);
    int d = lde<I64>(ei, (size_t)E + e);
    float norm = dinv[s] * dinv[d];
    atomicAdd(&a2[(size_t)d * 2 + 0], h2[(size_t)s * 2 + 0] * norm);
    atomicAdd(&a2[(size_t)d * 2 + 1], h2[(size_t)s * 2 + 1] * norm);
}
__global__ void fb_gemm1(const float* __restrict__ x, const float* __restrict__ W1,
                         float* __restrict__ h1, int n) {
    __shared__ float w[D_IN * D_HID];
    for (int i = threadIdx.x; i < D_IN * D_HID; i += blockDim.x) w[i] = W1[i];
    __syncthreads();
    int tid = blockIdx.x * blockDim.x + threadIdx.x;
    int node = tid >> 4, f = tid & 15;
    if (node >= n) return;
    const float4* xr = (const float4*)(x + (size_t)node * D_IN);
    float acc = 0.f;
#pragma unroll
    for (int k4 = 0; k4 < D_IN / 4; ++k4) {
        float4 v = xr[k4];
        int k = k4 * 4;
        acc += v.x * w[(k + 0) * D_HID + f];
        acc += v.y * w[(k + 1) * D_HID + f];
        acc += v.z * w[(k + 2) * D_HID + f];
        acc += v.w * w[(k + 3) * D_HID + f];
    }
    h1[tid] = acc;
}
__global__ void fb_lsm(const float* __restrict__ a2, float* __restrict__ out, int n) {
    int node = blockIdx.x * blockDim.x + threadIdx.x;
    if (node >= n) return;
    float v0 = a2[(size_t)node * 2 + 0];
    float v1 = a2[(size_t)node * 2 + 1];
    float m = fmaxf(v0, v1);
    float lse = m + logf(expf(v0 - m) + expf(v1 - m));
    out[(size_t)node * 2 + 0] = v0 - lse;
    out[(size_t)node * 2 + 1] = v1 - lse;
}

extern "C" void kernel_launch(void* const* d_in, const int* in_sizes, int n_in,
                              void* d_out, int out_size, void* d_ws, size_t ws_size,
                              hipStream_t stream) {
    const float* x  = (const float*)d_in[0];
    const void*  ei = d_in[1];
    const float* W1 = (const float*)d_in[2];
    const float* b1 = (const float*)d_in[3];
    const float* W2 = (const float*)d_in[4];
    const float* b2 = (const float*)d_in[5];

    const int N = in_sizes[0] / D_IN;      // 100000
    const int E = in_sizes[1] / 2;         // 3200000

    const int B = 256;
    dim3 blk(B);
    const int nBlkN = (N + B - 1) / B;     // 391
    const int nBlkE = (E + B - 1) / B;
    char* ws = (char*)d_ws;

    // CSR-path workspace layout (bytes)
    const size_t oDinv = 0;                        // N f32
    const size_t oDeg  = 400128;                   // N u32 (→ cursor)
    const size_t oRow  = 800256;                   // (N+1) int
    const size_t oBsum = 1200384;                  // 1024 int
    const size_t oCsr  = 1204608;                  // E int
    const size_t oG1   = oCsr + (size_t)E * 4;     // N*16 f32
    const size_t oG2   = oG1 + (size_t)N * D_HID * 4;  // N*2 f32
    const size_t oFlag = oG2 + (size_t)N * 2 * 4;
    const size_t needCSR = oFlag + 128;

    if (ws_size >= needCSR && nBlkN <= 1024) {
        float*        dinv    = (float*)(ws + oDinv);
        unsigned int* deg_cur = (unsigned int*)(ws + oDeg);
        int*          row_ptr = (int*)(ws + oRow);
        int*          bsums   = (int*)(ws + oBsum);
        int*          csr_src = (int*)(ws + oCsr);
        float*        g1      = (float*)(ws + oG1);
        float2*       g2      = (float2*)(ws + oG2);
        int*          flags   = (int*)(ws + oFlag);

        k_detect<<<dim3(1), blk, 0, stream>>>((const int*)ei, flags);

        k_deg_init<<<dim3(nBlkN), blk, 0, stream>>>(deg_cur, N);
        k_deg_count<false><<<dim3(nBlkE), blk, 0, stream>>>(ei, deg_cur, E, flags);
        k_deg_count<true ><<<dim3(nBlkE), blk, 0, stream>>>(ei, deg_cur, E, flags);
        k_dinv<<<dim3(nBlkN), blk, 0, stream>>>(deg_cur, dinv, N);

        k_scan1<<<dim3(nBlkN), blk, 0, stream>>>(deg_cur, row_ptr, bsums, N);
        k_scan2<<<dim3(1), dim3(1024), 0, stream>>>(bsums, nBlkN);
        k_scan3<<<dim3(nBlkN), blk, 0, stream>>>(row_ptr, bsums, deg_cur, N);

        k_fill<false><<<dim3(nBlkE), blk, 0, stream>>>(ei, deg_cur, csr_src, E, flags);
        k_fill<true ><<<dim3(nBlkE), blk, 0, stream>>>(ei, deg_cur, csr_src, E, flags);

        dim3 g_nh((N * D_HID + B - 1) / B);
        k_gemm1<<<g_nh, blk, 0, stream>>>(x, W1, dinv, g1, N);
        k_agg1f<<<g_nh, blk, 0, stream>>>(csr_src, row_ptr, dinv, g1, b1, W2, g2, N);
        k_agg2lsm<<<dim3(nBlkN), blk, 0, stream>>>(csr_src, row_ptr, dinv, g2, b2,
                                                   (float2*)d_out, N);
    } else {
        // fallback: round-3 atomic path (needs ~14.8 MB)
        float* dinv  = (float*)(ws + 0);
        float* h1    = (float*)(ws + 400128);
        float* a1    = (float*)(ws + 6800256);
        float* h2    = (float*)(ws + 13200384);
        float* a2    = (float*)(ws + 14000512);
        int*   flags = (int*)  (ws + 14800640);

        k_detect<<<dim3(1), blk, 0, stream>>>((const int*)ei, flags);
        k_deg_init<<<dim3(nBlkN), blk, 0, stream>>>((unsigned int*)dinv, N);
        k_deg_count<false><<<dim3(nBlkE), blk, 0, stream>>>(ei, (unsigned int*)dinv, E, flags);
        k_deg_count<true ><<<dim3(nBlkE), blk, 0, stream>>>(ei, (unsigned int*)dinv, E, flags);
        fb_dinv_inplace<<<dim3(nBlkN), blk, 0, stream>>>(dinv, N);

        dim3 g_nh((N * D_HID + B - 1) / B);
        fb_gemm1<<<g_nh, blk, 0, stream>>>(x, W1, h1, N);
        fb_a1_init<<<g_nh, blk, 0, stream>>>(h1, dinv, b1, a1, N);
        dim3 g_eh(((size_t)E * D_HID + B - 1) / B);
        fb_agg1<false><<<g_eh, blk, 0, stream>>>(ei, dinv, h1, a1, E, flags);
        fb_agg1<true ><<<g_eh, blk, 0, stream>>>(ei, dinv, h1, a1, E, flags);
        fb_relu_gemm2<<<dim3(nBlkN), blk, 0, stream>>>(a1, W2, h2, N);
        dim3 g_n2((N * N_CLS + B - 1) / B);
        fb_a2_init<<<g_n2, blk, 0, stream>>>(h2, dinv, b2, a2, N);
        fb_agg2<false><<<dim3(nBlkE), blk, 0, stream>>>(ei, dinv, h2, a2, E, flags);
        fb_agg2<true ><<<dim3(nBlkE), blk, 0, stream>>>(ei, dinv, h2, a2, E, flags);
        fb_lsm<<<dim3(nBlkN), blk, 0, stream>>>(a2, (float*)d_out, N);
    }
}